// Round 1
// baseline (2356.970 us; speedup 1.0000x reference)
//
#include <hip/hip_runtime.h>

#define N_NODES 100000
#define N_EDGES 1600000
#define IN_DIM 160
#define HID 128
#define BN_EPS 1e-5f

// ---------------------------------------------------------------------------
// CSR build: count in-degrees, exclusive-scan to rowptr, then bucket-fill the
// source list. Done once per launch; removes all per-feature atomics from the
// aggregation (660M float atomics -> 3.2M int atomics).
// ---------------------------------------------------------------------------

__global__ void count_deg_kernel(const int* __restrict__ dst, int* __restrict__ cnt) {
    int e = blockIdx.x * blockDim.x + threadIdx.x;
    if (e < N_EDGES) atomicAdd(&cnt[dst[e]], 1);
}

// Single-block chunked Hillis-Steele scan over N_NODES counts -> rowptr[N+1].
__global__ void scan_kernel(const int* __restrict__ cnt, int* __restrict__ rowptr) {
    __shared__ int buf[1024];
    __shared__ int carry_s;
    int t = threadIdx.x;
    if (t == 0) carry_s = 0;
    __syncthreads();
    for (int base = 0; base < N_NODES; base += 1024) {
        int v = (base + t < N_NODES) ? cnt[base + t] : 0;
        buf[t] = v;
        __syncthreads();
        for (int off = 1; off < 1024; off <<= 1) {
            int add = (t >= off) ? buf[t - off] : 0;
            __syncthreads();
            buf[t] += add;
            __syncthreads();
        }
        int incl = buf[t];
        int c = carry_s;
        if (base + t < N_NODES) rowptr[base + t] = c + incl - v;  // exclusive
        __syncthreads();
        if (t == 1023) carry_s = c + incl;
        __syncthreads();
    }
    if (t == 0) rowptr[N_NODES] = carry_s;
}

__global__ void fill_edges_kernel(const int* __restrict__ src, const int* __restrict__ dst,
                                  const int* __restrict__ rowptr, int* __restrict__ fill,
                                  int* __restrict__ eidx) {
    int e = blockIdx.x * blockDim.x + threadIdx.x;
    if (e < N_EDGES) {
        int d = dst[e];
        int pos = atomicAdd(&fill[d], 1);
        eidx[rowptr[d] + pos] = src[e];
    }
}

// ---------------------------------------------------------------------------
// Fused layer: per 64(or 32)-node tile: CSR gather-mean into LDS, then fp32
// VALU GEMM out = mean@wl + h@wr, BN(inference)+ReLU epilogue, store.
// LDS tile stores (mean, h) interleaved as float2 so phase-2 row reads are
// single ds_read_b64 broadcasts.
// ---------------------------------------------------------------------------

template <int D_IN, int NT, int TM>
__global__ __launch_bounds__(256) void sage_layer_kernel(
    const float* __restrict__ h_prev,   // [N, D_IN]
    const int* __restrict__ rowptr, const int* __restrict__ eidx,
    const float* __restrict__ wl, const float* __restrict__ wr,  // [D_IN][HID]
    const float* __restrict__ bl, const float* __restrict__ g,
    const float* __restrict__ be, const float* __restrict__ rm,
    const float* __restrict__ rv,
    float* __restrict__ h_out)          // [N, HID]
{
    __shared__ float2 tile[NT][D_IN];   // .x = mean, .y = h (root)
    const int t = threadIdx.x;
    const int wave = t >> 6;
    const int lane = t & 63;
    const int node0 = blockIdx.x * NT;
    constexpr int NCH = (D_IN + 63) / 64;

    // Phase 1: one wave per node (round-robin), lanes cover features.
    for (int r = wave; r < NT; r += 4) {
        int n = node0 + r;
        float acc[NCH];
#pragma unroll
        for (int cc = 0; cc < NCH; ++cc) acc[cc] = 0.f;
        int beg = 0, deg = 0;
        if (n < N_NODES) { beg = rowptr[n]; deg = rowptr[n + 1] - beg; }
        for (int i = 0; i < deg; ++i) {
            int s = eidx[beg + i];                       // wave-uniform
            const float* hp = h_prev + (long)s * D_IN;   // coalesced gather
#pragma unroll
            for (int cc = 0; cc < NCH; ++cc) {
                int c = lane + cc * 64;
                if (c < D_IN) acc[cc] += hp[c];
            }
        }
        float inv = 1.0f / fmaxf((float)deg, 1.0f);
        const float* hn = h_prev + (long)n * D_IN;
#pragma unroll
        for (int cc = 0; cc < NCH; ++cc) {
            int c = lane + cc * 64;
            if (c < D_IN) {
                float hv = (n < N_NODES) ? hn[c] : 0.f;
                tile[r][c] = make_float2(acc[cc] * inv, hv);
            }
        }
    }
    __syncthreads();

    // Phase 2: register-tiled fp32 GEMM. 256 threads = 32 col-groups x 8
    // row-groups; each thread computes TM rows x 4 cols.
    const int tx = t & 31;        // col group -> cols tx*4 .. tx*4+3
    const int ty = t >> 5;        // row group -> rows ty*TM .. ty*TM+TM-1
    const int j0 = tx * 4;
    const int r0 = ty * TM;
    float acc[TM][4];
#pragma unroll
    for (int r = 0; r < TM; ++r)
#pragma unroll
        for (int c = 0; c < 4; ++c) acc[r][c] = 0.f;

    for (int k = 0; k < D_IN; ++k) {
        float4 wlv = *(const float4*)(wl + k * HID + j0);
        float4 wrv = *(const float4*)(wr + k * HID + j0);
#pragma unroll
        for (int r = 0; r < TM; ++r) {
            float2 mh = tile[r0 + r][k];                 // LDS broadcast
            acc[r][0] += mh.x * wlv.x + mh.y * wrv.x;
            acc[r][1] += mh.x * wlv.y + mh.y * wrv.y;
            acc[r][2] += mh.x * wlv.z + mh.y * wrv.z;
            acc[r][3] += mh.x * wlv.w + mh.y * wrv.w;
        }
    }

    // Epilogue: BN (running stats) + ReLU, coalesced float4 stores.
    float4 scale, shift;
    {
        float sc[4], sh[4];
#pragma unroll
        for (int c = 0; c < 4; ++c) {
            int j = j0 + c;
            sc[c] = g[j] * rsqrtf(rv[j] + BN_EPS);
            sh[c] = (bl[j] - rm[j]) * sc[c] + be[j];
        }
        scale = make_float4(sc[0], sc[1], sc[2], sc[3]);
        shift = make_float4(sh[0], sh[1], sh[2], sh[3]);
    }
#pragma unroll
    for (int r = 0; r < TM; ++r) {
        int n = node0 + r0 + r;
        if (n < N_NODES) {
            float4 v;
            v.x = fmaxf(acc[r][0] * scale.x + shift.x, 0.f);
            v.y = fmaxf(acc[r][1] * scale.y + shift.y, 0.f);
            v.z = fmaxf(acc[r][2] * scale.z + shift.z, 0.f);
            v.w = fmaxf(acc[r][3] * scale.w + shift.w, 0.f);
            *(float4*)(h_out + (long)n * HID + j0) = v;
        }
    }
}

// ---------------------------------------------------------------------------
// Final linear: y[n] = dot(h[n], w) + b. One wave per node.
// ---------------------------------------------------------------------------
__global__ void final_linear_kernel(const float* __restrict__ h,
                                    const float* __restrict__ w,
                                    const float* __restrict__ b,
                                    float* __restrict__ out) {
    int wave = threadIdx.x >> 6, lane = threadIdx.x & 63;
    int n = blockIdx.x * 4 + wave;
    if (n >= N_NODES) return;
    const float* hp = h + (long)n * HID;
    float s = hp[lane] * w[lane] + hp[lane + 64] * w[lane + 64];
#pragma unroll
    for (int off = 32; off > 0; off >>= 1) s += __shfl_down(s, off);
    if (lane == 0) out[n] = s + b[0];
}

// ---------------------------------------------------------------------------

extern "C" void kernel_launch(void* const* d_in, const int* in_sizes, int n_in,
                              void* d_out, int out_size, void* d_ws, size_t ws_size,
                              hipStream_t stream) {
    const float* x    = (const float*)d_in[0];
    const int*   ei   = (const int*)d_in[1];
    const int*   esrc = ei;
    const int*   edst = ei + N_EDGES;
    // per-layer params: base index 2 + 7*i
    const float* wl[3]; const float* wr[3]; const float* bl[3];
    const float* g[3];  const float* be[3]; const float* rm[3]; const float* rv[3];
    for (int i = 0; i < 3; ++i) {
        wl[i] = (const float*)d_in[2 + 7 * i];
        wr[i] = (const float*)d_in[3 + 7 * i];
        bl[i] = (const float*)d_in[4 + 7 * i];
        g[i]  = (const float*)d_in[5 + 7 * i];
        be[i] = (const float*)d_in[6 + 7 * i];
        rm[i] = (const float*)d_in[7 + 7 * i];
        rv[i] = (const float*)d_in[8 + 7 * i];
    }
    const float* lin_w = (const float*)d_in[23];
    const float* lin_b = (const float*)d_in[24];
    float* out = (float*)d_out;

    // Workspace carve-up (256B aligned): rowptr, cnt, fill, eidx, h1, h2.
    char* ws = (char*)d_ws;
    size_t off = 0;
    auto carve = [&](size_t bytes) -> void* {
        void* p = ws + off;
        off += (bytes + 255) & ~(size_t)255;
        return p;
    };
    int*   rowptr = (int*)carve((N_NODES + 1) * sizeof(int));
    int*   cnt    = (int*)carve(N_NODES * sizeof(int));
    int*   fill   = (int*)carve(N_NODES * sizeof(int));
    int*   eidx   = (int*)carve(N_EDGES * sizeof(int));
    float* h1     = (float*)carve((size_t)N_NODES * HID * sizeof(float));
    float* h2     = (float*)carve((size_t)N_NODES * HID * sizeof(float));
    (void)ws_size; (void)n_in; (void)in_sizes; (void)out_size;

    hipMemsetAsync(cnt, 0, N_NODES * sizeof(int), stream);
    hipMemsetAsync(fill, 0, N_NODES * sizeof(int), stream);

    count_deg_kernel<<<(N_EDGES + 255) / 256, 256, 0, stream>>>(edst, cnt);
    scan_kernel<<<1, 1024, 0, stream>>>(cnt, rowptr);
    fill_edges_kernel<<<(N_EDGES + 255) / 256, 256, 0, stream>>>(esrc, edst, rowptr, fill, eidx);

    // Layer 0: D_IN=160, 32-node tiles (40KB LDS). Layers 1-2: 128, 64-node tiles (64KB LDS).
    sage_layer_kernel<IN_DIM, 32, 4><<<(N_NODES + 31) / 32, 256, 0, stream>>>(
        x, rowptr, eidx, wl[0], wr[0], bl[0], g[0], be[0], rm[0], rv[0], h1);
    sage_layer_kernel<HID, 64, 8><<<(N_NODES + 63) / 64, 256, 0, stream>>>(
        h1, rowptr, eidx, wl[1], wr[1], bl[1], g[1], be[1], rm[1], rv[1], h2);
    sage_layer_kernel<HID, 64, 8><<<(N_NODES + 63) / 64, 256, 0, stream>>>(
        h2, rowptr, eidx, wl[2], wr[2], bl[2], g[2], be[2], rm[2], rv[2], h1);

    final_linear_kernel<<<(N_NODES + 3) / 4, 256, 0, stream>>>(h1, lin_w, lin_b, out);
}

// Round 2
// 657.839 us; speedup vs baseline: 3.5829x; 3.5829x over previous
//
#include <hip/hip_runtime.h>

#define N_NODES 100000
#define N_EDGES 1600000
#define IN_DIM 160
#define HID 128
#define BN_EPS 1e-5f

#define M_PAD 100096   // 782 * 128 rows (GEMM block = 128 rows)
#define CNT_PAD 100352 // 98 * 1024
#define NBLK 98        // scan blocks
#define NPN 4          // nodes per wave in agg kernel

typedef unsigned int uint;
typedef unsigned short ushort;
typedef __attribute__((ext_vector_type(8))) short bf16x8;
typedef __attribute__((ext_vector_type(4))) float f32x4;

__device__ __forceinline__ ushort bf16rn(float f) {
    uint u = __float_as_uint(f);
    u += 0x7fffu + ((u >> 16) & 1u);
    return (ushort)(u >> 16);
}

// ---------------------------------------------------------------------------
// CSR build
// ---------------------------------------------------------------------------
__global__ void count_deg_kernel(const int* __restrict__ dst, int* __restrict__ cnt) {
    int e = blockIdx.x * blockDim.x + threadIdx.x;
    if (e < N_EDGES) atomicAdd(&cnt[dst[e]], 1);
}

// Per-1024-chunk sums (cnt padded+zeroed to CNT_PAD so int4 loads are safe).
__global__ void block_sum_kernel(const int* __restrict__ cnt, int* __restrict__ bsum) {
    int b = blockIdx.x, t = threadIdx.x;
    int4 v = ((const int4*)(cnt + b * 1024))[t];
    int s = v.x + v.y + v.z + v.w;
#pragma unroll
    for (int off = 32; off; off >>= 1) s += __shfl_down(s, off);
    __shared__ int wsum[4];
    if ((t & 63) == 0) wsum[t >> 6] = s;
    __syncthreads();
    if (t == 0) bsum[b] = wsum[0] + wsum[1] + wsum[2] + wsum[3];
}

// Exclusive scan of NBLK partials; single wave.
__global__ void scan_partials_kernel(const int* __restrict__ bsum, int* __restrict__ boff) {
    int lane = threadIdx.x;
    int carry = 0;
    for (int base = 0; base < NBLK; base += 64) {
        int v = (base + lane < NBLK) ? bsum[base + lane] : 0;
        int s = v;
#pragma unroll
        for (int off = 1; off <= 32; off <<= 1) {
            int t2 = __shfl_up(s, off);
            if (lane >= off) s += t2;
        }
        if (base + lane < NBLK) boff[base + lane] = carry + s - v;
        carry += __shfl(s, 63);
    }
}

// Final exclusive scan write: rowptr[i] for i in [0, CNT_PAD); rowptr[N_NODES]
// lands automatically (= N_EDGES) since padding counts are zero.
__global__ void scan_write_kernel(const int* __restrict__ cnt, const int* __restrict__ boff,
                                  int* __restrict__ rowptr) {
    int b = blockIdx.x, t = threadIdx.x;
    int4 v = ((const int4*)(cnt + b * 1024))[t];
    int ts = v.x + v.y + v.z + v.w;
    int s = ts;
#pragma unroll
    for (int off = 1; off <= 32; off <<= 1) {
        int t2 = __shfl_up(s, off);
        if ((t & 63) >= off) s += t2;
    }
    __shared__ int wpart[4];
    if ((t & 63) == 63) wpart[t >> 6] = s;
    __syncthreads();
    int woff = 0;
    for (int w = 0; w < (t >> 6); ++w) woff += wpart[w];
    int base = boff[b] + woff + (s - ts);
    int* rp = rowptr + b * 1024 + t * 4;
    rp[0] = base;
    rp[1] = base + v.x;
    rp[2] = base + v.x + v.y;
    rp[3] = base + v.x + v.y + v.z;
}

__global__ void fill_edges_kernel(const int* __restrict__ src, const int* __restrict__ dst,
                                  const int* __restrict__ rowptr, int* __restrict__ fill,
                                  int* __restrict__ eidx) {
    int e = blockIdx.x * blockDim.x + threadIdx.x;
    if (e < N_EDGES) {
        int d = dst[e];
        int pos = atomicAdd(&fill[d], 1);
        eidx[rowptr[d] + pos] = src[e];
    }
}

// ---------------------------------------------------------------------------
// Prep: weights -> Bt[256][K] bf16 (Bt[n][k] = n<128 ? wl[k][n] : wr[k][n-128]);
// BN -> scale/shift with bl folded in.
// ---------------------------------------------------------------------------
__global__ void prep_weights_kernel(const float* __restrict__ wl, const float* __restrict__ wr,
                                    ushort* __restrict__ Bt, int K) {
    int n = blockIdx.y;
    int k = blockIdx.x * 64 + threadIdx.x;
    if (k < K) {
        float v = (n < HID) ? wl[k * HID + n] : wr[k * HID + (n - HID)];
        Bt[n * K + k] = bf16rn(v);
    }
}

__global__ void bn_prep_kernel(const float* __restrict__ bl, const float* __restrict__ g,
                               const float* __restrict__ be, const float* __restrict__ rm,
                               const float* __restrict__ rv, float* __restrict__ scale,
                               float* __restrict__ shift) {
    int j = threadIdx.x;
    float s = g[j] * rsqrtf(rv[j] + BN_EPS);
    scale[j] = s;
    shift[j] = (bl[j] - rm[j]) * s + be[j];
}

// ---------------------------------------------------------------------------
// GEMM: t = A @ [wl | wr].  A: [M_PAD, K] (bf16, padded) or [N_NODES, K] fp32.
// Bt: [256, K] bf16.  Out: tl = t[:, :128] bf16, tr = t[:, 128:] fp32.
// Block = 256 thr (4 waves), 128 M-rows/block; wave = 32 rows x 256 cols via
// 2x16 tiles of mfma_f32_16x16x32_bf16.
// ---------------------------------------------------------------------------
template <int K, bool AFP32>
__global__ __launch_bounds__(256) void gemm_kernel(const void* __restrict__ A_,
                                                   const ushort* __restrict__ Bt,
                                                   ushort* __restrict__ tl,
                                                   float* __restrict__ tr) {
    const int lane = threadIdx.x & 63;
    const int wv = threadIdx.x >> 6;
    const int col = lane & 15;
    const int kq = (lane >> 4) * 8;
    const int m0 = blockIdx.x * 128 + wv * 32 + col;  // A row for tile 0
    f32x4 acc[2][16];
#pragma unroll
    for (int a = 0; a < 2; ++a)
#pragma unroll
        for (int t = 0; t < 16; ++t) acc[a][t] = (f32x4){0.f, 0.f, 0.f, 0.f};

#pragma unroll
    for (int k0 = 0; k0 < K; k0 += 32) {
        int kk = k0 + kq;
        bf16x8 a0, a1;
        if (AFP32) {
            const float* A = (const float*)A_;
            float4 z = make_float4(0.f, 0.f, 0.f, 0.f);
            float4 f00 = z, f01 = z, f10 = z, f11 = z;
            if (m0 < N_NODES) {
                f00 = *(const float4*)(A + (size_t)m0 * K + kk);
                f01 = *(const float4*)(A + (size_t)m0 * K + kk + 4);
            }
            if (m0 + 16 < N_NODES) {
                f10 = *(const float4*)(A + (size_t)(m0 + 16) * K + kk);
                f11 = *(const float4*)(A + (size_t)(m0 + 16) * K + kk + 4);
            }
            a0[0] = (short)bf16rn(f00.x); a0[1] = (short)bf16rn(f00.y);
            a0[2] = (short)bf16rn(f00.z); a0[3] = (short)bf16rn(f00.w);
            a0[4] = (short)bf16rn(f01.x); a0[5] = (short)bf16rn(f01.y);
            a0[6] = (short)bf16rn(f01.z); a0[7] = (short)bf16rn(f01.w);
            a1[0] = (short)bf16rn(f10.x); a1[1] = (short)bf16rn(f10.y);
            a1[2] = (short)bf16rn(f10.z); a1[3] = (short)bf16rn(f10.w);
            a1[4] = (short)bf16rn(f11.x); a1[5] = (short)bf16rn(f11.y);
            a1[6] = (short)bf16rn(f11.z); a1[7] = (short)bf16rn(f11.w);
        } else {
            const ushort* A = (const ushort*)A_;
            a0 = *(const bf16x8*)(A + (size_t)m0 * K + kk);
            a1 = *(const bf16x8*)(A + (size_t)(m0 + 16) * K + kk);
        }
#pragma unroll
        for (int t = 0; t < 16; ++t) {
            bf16x8 b = *(const bf16x8*)(Bt + (size_t)(t * 16 + col) * K + kk);
            acc[0][t] = __builtin_amdgcn_mfma_f32_16x16x32_bf16(a0, b, acc[0][t], 0, 0, 0);
            acc[1][t] = __builtin_amdgcn_mfma_f32_16x16x32_bf16(a1, b, acc[1][t], 0, 0, 0);
        }
    }

    // Epilogue: C/D layout col=lane&15, row=(lane>>4)*4+reg.
    const int quad = lane >> 4;
#pragma unroll
    for (int mt = 0; mt < 2; ++mt) {
        int mbase = blockIdx.x * 128 + wv * 32 + mt * 16 + quad * 4;
#pragma unroll
        for (int t = 0; t < 16; ++t) {
            int n = t * 16 + col;
#pragma unroll
            for (int r = 0; r < 4; ++r) {
                int m = mbase + r;  // < M_PAD by construction; pad rows are scratch
                float v = acc[mt][t][r];
                if (t < 8) tl[(size_t)m * HID + n] = bf16rn(v);
                else       tr[(size_t)m * HID + (n - HID)] = v;
            }
        }
    }
}

// ---------------------------------------------------------------------------
// Aggregation + BN + ReLU (+ fused final linear for last layer).
// One wave per NPN consecutive nodes; lane covers feature pair (2L, 2L+1).
// Edge gathers issued 8-at-a-time (masked) for MLP; edge ids via scalar loads.
// ---------------------------------------------------------------------------
template <bool FINAL>
__global__ __launch_bounds__(256) void agg_kernel(
    const ushort* __restrict__ tl_, const float* __restrict__ tr,
    const int* __restrict__ rowptr, const int* __restrict__ eidx,
    const float* __restrict__ bnscale, const float* __restrict__ bnshift,
    const float* __restrict__ linw, const float* __restrict__ linb,
    ushort* __restrict__ hout, float* __restrict__ out) {
    const uint* tl = (const uint*)tl_;
    const int lane = threadIdx.x & 63;
    const int wv = (blockIdx.x * 256 + (int)threadIdx.x) >> 6;
    float2 sc = *(const float2*)(bnscale + 2 * lane);
    float2 sh = *(const float2*)(bnshift + 2 * lane);
    float w0 = 0.f, w1 = 0.f, lb = 0.f;
    if (FINAL) {
        float2 wvv = *(const float2*)(linw + 2 * lane);
        w0 = wvv.x; w1 = wvv.y; lb = linb[0];
    }
    const int n0 = wv * NPN;
    for (int i = 0; i < NPN; ++i) {
        int n = n0 + i;
        if (n >= N_NODES) return;
        int beg = __builtin_amdgcn_readfirstlane(rowptr[n]);
        int end = __builtin_amdgcn_readfirstlane(rowptr[n + 1]);
        float s0 = 0.f, s1 = 0.f;
        for (int e = beg; e < end; e += 8) {
            int c = end - e;
            uint u[8];
#pragma unroll
            for (int j = 0; j < 8; ++j) {
                int ee = (j < c) ? (e + j) : beg;
                int s = eidx[ee];
                u[j] = tl[s * 64 + lane];
            }
#pragma unroll
            for (int j = 0; j < 8; ++j) {
                float f0 = __uint_as_float(u[j] << 16);
                float f1 = __uint_as_float(u[j] & 0xffff0000u);
                if (j < c) { s0 += f0; s1 += f1; }
            }
        }
        int deg = end - beg;
        float inv = 1.0f / (float)max(deg, 1);
        float2 tv = *(const float2*)(tr + (size_t)n * HID + 2 * lane);
        float o0 = fmaxf((s0 * inv + tv.x) * sc.x + sh.x, 0.f);
        float o1 = fmaxf((s1 * inv + tv.y) * sc.y + sh.y, 0.f);
        if (FINAL) {
            float p = o0 * w0 + o1 * w1;
#pragma unroll
            for (int off = 32; off; off >>= 1) p += __shfl_down(p, off);
            if (lane == 0) out[n] = p + lb;
        } else {
            uint pack = (uint)bf16rn(o0) | ((uint)bf16rn(o1) << 16);
            ((uint*)hout)[n * 64 + lane] = pack;
        }
    }
}

// ---------------------------------------------------------------------------

extern "C" void kernel_launch(void* const* d_in, const int* in_sizes, int n_in,
                              void* d_out, int out_size, void* d_ws, size_t ws_size,
                              hipStream_t stream) {
    const float* x    = (const float*)d_in[0];
    const int*   ei   = (const int*)d_in[1];
    const int*   esrc = ei;
    const int*   edst = ei + N_EDGES;
    const float* wl[3]; const float* wr[3]; const float* bl[3];
    const float* g[3];  const float* be[3]; const float* rm[3]; const float* rv[3];
    for (int i = 0; i < 3; ++i) {
        wl[i] = (const float*)d_in[2 + 7 * i];
        wr[i] = (const float*)d_in[3 + 7 * i];
        bl[i] = (const float*)d_in[4 + 7 * i];
        g[i]  = (const float*)d_in[5 + 7 * i];
        be[i] = (const float*)d_in[6 + 7 * i];
        rm[i] = (const float*)d_in[7 + 7 * i];
        rv[i] = (const float*)d_in[8 + 7 * i];
    }
    const float* lin_w = (const float*)d_in[23];
    const float* lin_b = (const float*)d_in[24];
    float* out = (float*)d_out;

    // Workspace carve-up (total ~109.5 MB; cnt/fill/bsum/boff alias tr).
    char* ws = (char*)d_ws;
    size_t off = 0;
    auto carve = [&](size_t bytes) -> void* {
        void* p = ws + off;
        off += (bytes + 255) & ~(size_t)255;
        return p;
    };
    int*    rowptr = (int*)carve((size_t)(CNT_PAD + 4) * sizeof(int));
    int*    eidx   = (int*)carve((size_t)N_EDGES * sizeof(int));
    ushort* tl     = (ushort*)carve((size_t)M_PAD * HID * sizeof(ushort));
    float*  tr     = (float*)carve((size_t)M_PAD * HID * sizeof(float));
    ushort* h      = (ushort*)carve((size_t)M_PAD * HID * sizeof(ushort));
    ushort* Bt0    = (ushort*)carve(256 * IN_DIM * sizeof(ushort));
    ushort* Bt1    = (ushort*)carve(256 * HID * sizeof(ushort));
    ushort* Bt2    = (ushort*)carve(256 * HID * sizeof(ushort));
    float*  bnsc   = (float*)carve(3 * HID * sizeof(float));
    float*  bnsh   = (float*)carve(3 * HID * sizeof(float));
    // CSR temporaries alias the tr buffer (dead before tr's first write).
    int* cnt  = (int*)tr;
    int* fill = (int*)tr + CNT_PAD;
    int* bsum = (int*)tr + CNT_PAD + N_NODES;
    int* boff = bsum + NBLK;
    (void)ws_size; (void)n_in; (void)in_sizes; (void)out_size;

    hipMemsetAsync(cnt, 0, CNT_PAD * sizeof(int), stream);
    hipMemsetAsync(fill, 0, N_NODES * sizeof(int), stream);

    count_deg_kernel<<<(N_EDGES + 255) / 256, 256, 0, stream>>>(edst, cnt);
    block_sum_kernel<<<NBLK, 256, 0, stream>>>(cnt, bsum);
    scan_partials_kernel<<<1, 64, 0, stream>>>(bsum, boff);
    scan_write_kernel<<<NBLK, 256, 0, stream>>>(cnt, boff, rowptr);
    fill_edges_kernel<<<(N_EDGES + 255) / 256, 256, 0, stream>>>(esrc, edst, rowptr, fill, eidx);

    prep_weights_kernel<<<dim3((IN_DIM + 63) / 64, 256), 64, 0, stream>>>(wl[0], wr[0], Bt0, IN_DIM);
    prep_weights_kernel<<<dim3((HID + 63) / 64, 256), 64, 0, stream>>>(wl[1], wr[1], Bt1, HID);
    prep_weights_kernel<<<dim3((HID + 63) / 64, 256), 64, 0, stream>>>(wl[2], wr[2], Bt2, HID);
    bn_prep_kernel<<<1, HID, 0, stream>>>(bl[0], g[0], be[0], rm[0], rv[0], bnsc, bnsh);
    bn_prep_kernel<<<1, HID, 0, stream>>>(bl[1], g[1], be[1], rm[1], rv[1], bnsc + HID, bnsh + HID);
    bn_prep_kernel<<<1, HID, 0, stream>>>(bl[2], g[2], be[2], rm[2], rv[2], bnsc + 2 * HID, bnsh + 2 * HID);

    const int GEMM_GRID = M_PAD / 128;             // 782
    const int AGG_GRID = N_NODES / (4 * NPN);      // 6250

    gemm_kernel<IN_DIM, true><<<GEMM_GRID, 256, 0, stream>>>(x, Bt0, tl, tr);
    agg_kernel<false><<<AGG_GRID, 256, 0, stream>>>(tl, tr, rowptr, eidx, bnsc, bnsh,
                                                    nullptr, nullptr, h, nullptr);
    gemm_kernel<HID, false><<<GEMM_GRID, 256, 0, stream>>>(h, Bt1, tl, tr);
    agg_kernel<false><<<AGG_GRID, 256, 0, stream>>>(tl, tr, rowptr, eidx, bnsc + HID, bnsh + HID,
                                                    nullptr, nullptr, h, nullptr);
    gemm_kernel<HID, false><<<GEMM_GRID, 256, 0, stream>>>(h, Bt2, tl, tr);
    agg_kernel<true><<<AGG_GRID, 256, 0, stream>>>(tl, tr, rowptr, eidx, bnsc + 2 * HID, bnsh + 2 * HID,
                                                   lin_w, lin_b, nullptr, out);
}